// Round 14
// baseline (268.459 us; speedup 1.0000x reference)
//
#include <hip/hip_runtime.h>
#include <hip/hip_bf16.h>

#define DEV __device__ __forceinline__

typedef __bf16 bf16;
typedef __bf16 bf16x4 __attribute__((ext_vector_type(4)));
typedef __bf16 bf16x8 __attribute__((ext_vector_type(8)));
typedef float f32x4 __attribute__((ext_vector_type(4)));

static constexpr int Bb = 4, Ll = 2048, Dd = 512, Ee = 8, Hh = 1024;
static constexpr int Mm = Bb * Ll;  // 8192 tokens
static constexpr int GKS = Ee * Hh; // 8192 (w2t row stride)
// G stored BLOCK-TILED: tile (e, mt, ct) = [256 m'][256 h'] contiguous 128KB.
static constexpr int TSZ = 65536;   // elements per tile

// ---------------- async global->LDS (16B per lane, wave-uniform LDS base) ---
DEV void gload_lds16(const void* g, void* l) {
  __builtin_amdgcn_global_load_lds(
      (const __attribute__((address_space(1))) unsigned int*)g,
      (__attribute__((address_space(3))) unsigned int*)l, 16, 0, 0);
}

// fast exact-enough gelu: tanh form, g = h - h/(exp(2y)+1)
DEV float gelu_fast(float h) {
  const float k = 0.7978845608028654f * 2.0f * 1.4426950408889634f;
  float h2 = h * h;
  float y = h * (k + (0.044715f * k) * h2);
  float t = exp2f(y);
  return h - h * __frcp_rn(t + 1.0f);
}

// ---------------- elementwise f32 -> bf16 -----------------------------------
__global__ void cvt_x_kernel(const float* __restrict__ in, bf16* __restrict__ out, int n4) {
  int i = blockIdx.x * blockDim.x + threadIdx.x;
  if (i < n4) {
    float4 v = ((const float4*)in)[i];
    bf16x4 o = {(bf16)v.x, (bf16)v.y, (bf16)v.z, (bf16)v.w};
    ((bf16x4*)out)[i] = o;
  }
}

// ---------------- tiled transpose + convert ---------------------------------
__global__ void transpose_cvt(const float* __restrict__ in, bf16* __restrict__ out,
                              int R, int C, size_t in_es, size_t out_es, int out_rs) {
  __shared__ float tile[64][65];
  const int e = blockIdx.z;
  const float* ip = in + (size_t)e * in_es;
  bf16* op = out + (size_t)e * out_es;
  const int r0 = blockIdx.y * 64, c0 = blockIdx.x * 64;
  const int tc = threadIdx.x & 63, tr = threadIdx.x >> 6;
#pragma unroll
  for (int i = 0; i < 16; ++i) {
    const int r = tr + i * 4;
    tile[r][tc] = ip[(size_t)(r0 + r) * C + c0 + tc];
  }
  __syncthreads();
  const int wr = threadIdx.x & 63, wc0 = threadIdx.x >> 6;
#pragma unroll
  for (int i = 0; i < 16; ++i) {
    const int c = wc0 + i * 4;
    op[(size_t)(c0 + c) * out_rs + r0 + wr] = (bf16)tile[wr][c];
  }
}

// ============ 256x256, BK=32, triple-buffered fine-interleave core ==========
#define PIPE_DECLS                                                   \
  const int t = threadIdx.x;                                         \
  const int lane = t & 63;                                           \
  const int wid = t >> 6;                                            \
  const int wm = wid >> 2, wn = wid & 3;                             \
  const int fr = lane & 15, fg = lane >> 4, fq = lane >> 4;          \
  const int srow = t >> 2;                                           \
  const int sq = (t & 3) ^ ((t >> 3) & 3);                           \
  const int rsl = fg ^ ((fr >> 1) & 3);

#define PHASE0(buf)                                                  \
  bf16x8 bfr[4], af[4];                                              \
  _Pragma("unroll") for (int fj = 0; fj < 4; ++fj) {                 \
    const int row = wn * 64 + fj * 16 + fr;                          \
    bfr[fj] = *(const bf16x8*)((buf) + 16384 + row * 64 + rsl * 16); \
  }                                                                  \
  _Pragma("unroll") for (int fi = 0; fi < 4; ++fi) {                 \
    const int row = wm * 128 + fi * 16 + fr;                         \
    af[fi] = *(const bf16x8*)((buf) + row * 64 + rsl * 16);          \
  }

#define PHASE1_READS(buf)                                            \
  bf16x8 af2[4];                                                     \
  _Pragma("unroll") for (int fi = 0; fi < 4; ++fi) {                 \
    const int row = wm * 128 + (4 + fi) * 16 + fr;                   \
    af2[fi] = *(const bf16x8*)((buf) + row * 64 + rsl * 16);         \
  }

#define MFMA_CLUSTER(A, ACCOFF)                                      \
  __builtin_amdgcn_s_barrier();                                      \
  asm volatile("s_waitcnt lgkmcnt(0)" ::: "memory");                 \
  __builtin_amdgcn_sched_barrier(0);                                 \
  __builtin_amdgcn_s_setprio(1);                                     \
  _Pragma("unroll") for (int fi = 0; fi < 4; ++fi)                   \
  _Pragma("unroll") for (int fj = 0; fj < 4; ++fj)                   \
    acc[(ACCOFF) + fi][fj] = __builtin_amdgcn_mfma_f32_16x16x32_bf16(\
        bfr[fj], (A)[fi], acc[(ACCOFF) + fi][fj], 0, 0, 0);          \
  __builtin_amdgcn_s_setprio(0);

// ---------------- stage 1: persistent over ct, SPREAD-STORE epilogue --------
// Stores count in vmcnt on CDNA and vmcnt decrements IN ORDER, so a burst of
// 32 epilogue stores followed by vmcnt(4) stalls the whole pipeline until the
// stores retire (4 synchronized ~33MB bursts across the grid = ~44us). Fix:
// pack window ct's results into gout regs, then issue 2 stores per body of
// window ct+1 right after the top barrier. Issue order per body:
// st^2 < ld^4(it+2). Wait schedule (younger-than-loads(it) counting):
//   it <= 16 : vmcnt(4)  (no stores yet in previous body)
//   17..62   : vmcnt(6)  (st^2(it-1) + ld^4(it+1) in flight)
//   it = 63  : vmcnt(2)  (no loads staged by body 62; st^2(62) in flight)
// Final window bursts after the loop (kernel end; nothing waits on it).
__global__ __launch_bounds__(512, 1) void ffn_stage1_f(
    const bf16* __restrict__ xb, const bf16* __restrict__ w1t,
    const float* __restrict__ b1, const float* __restrict__ wts,
    bf16* __restrict__ G) {
  __shared__ __align__(16) char lds[98304];
  __shared__ float b1s[1024];
  __shared__ float wls[256];
  const int mt = blockIdx.x, e = blockIdx.y;
  PIPE_DECLS
  b1s[t] = b1[e * Hh + t];
  b1s[512 + t] = b1[e * Hh + 512 + t];
  if (t < 256) wls[t] = wts[((size_t)mt * 256 + t) * Ee + e];

  const bf16* Ag = xb + (size_t)mt * 256 * Dd;
  const bf16* Bg0 = w1t + (size_t)e * Hh * Dd;

  auto stageA = [&](int it, char* buf) {
    const int k0 = (it & 15) * 32;
    gload_lds16(Ag + (size_t)srow * Dd + k0 + sq * 8, buf + wid * 1024);
    gload_lds16(Ag + (size_t)(128 + srow) * Dd + k0 + sq * 8, buf + 8192 + wid * 1024);
  };
  auto stageB = [&](int it, char* buf) {
    const bf16* Bg = Bg0 + (size_t)(it >> 4) * 256 * Dd;
    const int k0 = (it & 15) * 32;
    gload_lds16(Bg + (size_t)srow * Dd + k0 + sq * 8, buf + 16384 + wid * 1024);
    gload_lds16(Bg + (size_t)(128 + srow) * Dd + k0 + sq * 8, buf + 24576 + wid * 1024);
  };

  f32x4 acc[8][4] = {};
  bf16x4 gout[8][4];
  bf16* gprev = G;  // set at end of each window; guarded by ct>0 before use
  stageA(0, lds); stageB(0, lds);
  stageA(1, lds + 32768); stageB(1, lds + 32768);

  for (int ct = 0; ct < 4; ++ct) {
#pragma unroll
    for (int kt = 0; kt < 16; ++kt) {
      const int it = ct * 16 + kt;
      if (ct == 0 || (ct == 1 && kt == 0)) {
        asm volatile("s_waitcnt vmcnt(4)" ::: "memory");
      } else if (ct == 3 && kt == 15) {
        asm volatile("s_waitcnt vmcnt(2)" ::: "memory");
      } else {
        asm volatile("s_waitcnt vmcnt(6)" ::: "memory");
      }
      __builtin_amdgcn_s_barrier();
      if (ct > 0) {  // dribble previous window's stores: 2 per body
        *(bf16x4*)(gprev + (kt >> 1) * 4096 + ((kt & 1) * 2) * 16) =
            gout[kt >> 1][(kt & 1) * 2];
        *(bf16x4*)(gprev + (kt >> 1) * 4096 + ((kt & 1) * 2 + 1) * 16) =
            gout[kt >> 1][(kt & 1) * 2 + 1];
      }
      char* buf = lds + (it % 3) * 32768;
      char* nbuf = lds + ((it + 2) % 3) * 32768;
      PHASE0(buf)
      if (it + 2 < 64) stageA(it + 2, nbuf);
      MFMA_CLUSTER(af, 0)
      PHASE1_READS(buf)
      if (it + 2 < 64) stageB(it + 2, nbuf);
      MFMA_CLUSTER(af2, 4)
    }
    // pack window ct into gout (gelu + weight), re-zero acc
    bf16* tbase = G + ((((size_t)e * 32 + mt) * 4) + ct) * TSZ;
    gprev = tbase + ((size_t)(wm * 128 + fr)) * 256 + wn * 64 + fq * 4;
    float b1v[4][4];
#pragma unroll
    for (int fj = 0; fj < 4; ++fj)
#pragma unroll
      for (int r = 0; r < 4; ++r)
        b1v[fj][r] = b1s[ct * 256 + wn * 64 + fj * 16 + fq * 4 + r];
#pragma unroll
    for (int fi = 0; fi < 8; ++fi) {
      const float wgt = wls[wm * 128 + fi * 16 + fr];
#pragma unroll
      for (int fj = 0; fj < 4; ++fj) {
#pragma unroll
        for (int r = 0; r < 4; ++r) {
          float v = acc[fi][fj][r] + b1v[fj][r];
          gout[fi][fj][r] = (bf16)(gelu_fast(v) * wgt);
          acc[fi][fj][r] = 0.f;
        }
      }
    }
  }
  // final window (ct=3) burst-store: nothing waits on these
#pragma unroll
  for (int fi = 0; fi < 8; ++fi)
#pragma unroll
    for (int fj = 0; fj < 4; ++fj)
      *(bf16x4*)(gprev + fi * 4096 + fj * 16) = gout[fi][fj];
}

// ---------------- stage 2: split-K partial, tiled-G reads (R13 proven) ------
__global__ __launch_bounds__(512, 1) void ffn_stage2_f(
    const bf16* __restrict__ G, const bf16* __restrict__ w2t,
    float* __restrict__ P, int eslabs) {
  __shared__ __align__(16) char lds[98304];
  const int mt = blockIdx.x, nt = blockIdx.y, s = blockIdx.z;
  PIPE_DECLS
  const bf16* Bg = w2t + (size_t)nt * 256 * GKS + (size_t)s * eslabs * Hh;

  auto stageA = [&](int it, char* buf) {
    const int eidx = s * eslabs + (it >> 5);
    const int ct = (it >> 3) & 3;
    const int hp = (it & 7) * 32;
    const bf16* tb = G + ((((size_t)eidx * 32 + mt) * 4) + ct) * TSZ;
    gload_lds16(tb + (size_t)srow * 256 + hp + sq * 8, buf + wid * 1024);
    gload_lds16(tb + (size_t)(128 + srow) * 256 + hp + sq * 8, buf + 8192 + wid * 1024);
  };
  auto stageB = [&](int it, char* buf) {
    const int k0 = it * 32;
    gload_lds16(Bg + (size_t)srow * GKS + k0 + sq * 8, buf + 16384 + wid * 1024);
    gload_lds16(Bg + (size_t)(128 + srow) * GKS + k0 + sq * 8, buf + 24576 + wid * 1024);
  };

  f32x4 acc[8][4] = {};
  const int NT = eslabs * 32;
  stageA(0, lds); stageB(0, lds);
  stageA(1, lds + 32768); stageB(1, lds + 32768);
  for (int it = 0; it < NT; ++it) {
    char* buf = lds + (it % 3) * 32768;
    char* nbuf = lds + ((it + 2) % 3) * 32768;
    if (it + 1 < NT) {
      asm volatile("s_waitcnt vmcnt(4)" ::: "memory");
    } else {
      asm volatile("s_waitcnt vmcnt(0)" ::: "memory");
    }
    __builtin_amdgcn_s_barrier();
    {
      PHASE0(buf)
      if (it + 2 < NT) stageA(it + 2, nbuf);
      MFMA_CLUSTER(af, 0)
      PHASE1_READS(buf)
      if (it + 2 < NT) stageB(it + 2, nbuf);
      MFMA_CLUSTER(af2, 4)
    }
  }

  float* Pp = P + (size_t)s * Mm * Dd;
#pragma unroll
  for (int fi = 0; fi < 8; ++fi) {
    const size_t m = (size_t)mt * 256 + wm * 128 + fi * 16 + fr;
    float* pp = Pp + m * Dd + nt * 256 + wn * 64 + fq * 4;
#pragma unroll
    for (int fj = 0; fj < 4; ++fj) *(f32x4*)(pp + fj * 16) = acc[fi][fj];
  }
}

// ---------------- reduce partials + bias ------------------------------------
__global__ __launch_bounds__(256) void reduce_bias(
    const float* __restrict__ P, const float* __restrict__ wts,
    const float* __restrict__ b2, float* __restrict__ out, int S) {
  const int n4 = Mm * Dd / 4;
  int i = blockIdx.x * 256 + threadIdx.x;
  if (i >= n4) return;
  const int m = i / (Dd / 4);
  const int d0 = (i % (Dd / 4)) * 4;
  float4 a = ((const float4*)P)[i];
  for (int s = 1; s < S; ++s) {
    float4 p = ((const float4*)P)[(size_t)s * n4 + i];
    a.x += p.x; a.y += p.y; a.z += p.z; a.w += p.w;
  }
  const float* wr = wts + (size_t)m * Ee;
#pragma unroll
  for (int e = 0; e < Ee; ++e) {
    const float w = wr[e];
    float4 b = *(const float4*)(b2 + e * Dd + d0);
    a.x += w * b.x; a.y += w * b.y; a.z += w * b.z; a.w += w * b.w;
  }
  ((float4*)out)[i] = a;
}

// ---------------- launch ----------------------------------------------------
extern "C" void kernel_launch(void* const* d_in, const int* in_sizes, int n_in,
                              void* d_out, int out_size, void* d_ws, size_t ws_size,
                              hipStream_t stream) {
  const float* x   = (const float*)d_in[0];
  const float* wts = (const float*)d_in[1];
  const float* w1  = (const float*)d_in[2];
  const float* b1  = (const float*)d_in[3];
  const float* w2  = (const float*)d_in[4];
  const float* b2  = (const float*)d_in[5];
  float* out = (float*)d_out;

  char* ws = (char*)d_ws;
  size_t off = 0;
  bf16* xb  = (bf16*)(ws + off); off += (size_t)Mm * Dd * 2;
  bf16* w1t = (bf16*)(ws + off); off += (size_t)Ee * Hh * Dd * 2;
  bf16* w2t = (bf16*)(ws + off); off += (size_t)Dd * Ee * Hh * 2;

  const size_t gfull = (size_t)Mm * Ee * Hh * 2;  // 134 MB (tiled layout)
  const size_t psz   = (size_t)Mm * Dd * 4;       // 16.8 MB

  cvt_x_kernel<<<(Mm * Dd / 4 + 255) / 256, 256, 0, stream>>>(x, xb, Mm * Dd / 4);
  transpose_cvt<<<dim3(Hh / 64, Dd / 64, Ee), 256, 0, stream>>>(
      w1, w1t, Dd, Hh, (size_t)Dd * Hh, (size_t)Hh * Dd, Dd);
  transpose_cvt<<<dim3(Dd / 64, Hh / 64, Ee), 256, 0, stream>>>(
      w2, w2t, Hh, Dd, (size_t)Hh * Dd, (size_t)Hh, Ee * Hh);

  int S = 0;
  if (ws_size >= off + gfull + 4 * psz) S = 4;
  else if (ws_size >= off + gfull + 2 * psz) S = 2;

  if (S >= 2) {
    bf16* G = (bf16*)(ws + off);
    float* P = (float*)(ws + off + gfull);
    ffn_stage1_f<<<dim3(Mm / 256, Ee), 512, 0, stream>>>(
        xb, w1t, b1, wts, G);
    ffn_stage2_f<<<dim3(Mm / 256, Dd / 256, S), 512, 0, stream>>>(
        G, w2t, P, Ee / S);
    reduce_bias<<<(Mm * Dd / 4 + 255) / 256, 256, 0, stream>>>(P, wts, b2, out, S);
  }
}

// Round 15
// 253.115 us; speedup vs baseline: 1.0606x; 1.0606x over previous
//
#include <hip/hip_runtime.h>
#include <hip/hip_bf16.h>

#define DEV __device__ __forceinline__

typedef __bf16 bf16;
typedef __bf16 bf16x4 __attribute__((ext_vector_type(4)));
typedef __bf16 bf16x8 __attribute__((ext_vector_type(8)));
typedef float f32x4 __attribute__((ext_vector_type(4)));

static constexpr int Bb = 4, Ll = 2048, Dd = 512, Ee = 8, Hh = 1024;
static constexpr int Mm = Bb * Ll;  // 8192 tokens
static constexpr int GKS = Ee * Hh; // 8192 (w2t row stride)
// G stored BLOCK-TILED: tile (e, mt, ct) = [256 m'][256 h'] contiguous 128KB.
static constexpr int TSZ = 65536;   // elements per tile

// ---------------- async global->LDS (16B per lane, wave-uniform LDS base) ---
DEV void gload_lds16(const void* g, void* l) {
  __builtin_amdgcn_global_load_lds(
      (const __attribute__((address_space(1))) unsigned int*)g,
      (__attribute__((address_space(3))) unsigned int*)l, 16, 0, 0);
}

// fast exact-enough gelu: tanh form, g = h - h/(exp(2y)+1)
DEV float gelu_fast(float h) {
  const float k = 0.7978845608028654f * 2.0f * 1.4426950408889634f;
  float h2 = h * h;
  float y = h * (k + (0.044715f * k) * h2);
  float t = exp2f(y);
  return h - h * __frcp_rn(t + 1.0f);
}

// ---------------- elementwise f32 -> bf16 -----------------------------------
__global__ void cvt_x_kernel(const float* __restrict__ in, bf16* __restrict__ out, int n4) {
  int i = blockIdx.x * blockDim.x + threadIdx.x;
  if (i < n4) {
    float4 v = ((const float4*)in)[i];
    bf16x4 o = {(bf16)v.x, (bf16)v.y, (bf16)v.z, (bf16)v.w};
    ((bf16x4*)out)[i] = o;
  }
}

// ---------------- tiled transpose + convert ---------------------------------
__global__ void transpose_cvt(const float* __restrict__ in, bf16* __restrict__ out,
                              int R, int C, size_t in_es, size_t out_es, int out_rs) {
  __shared__ float tile[64][65];
  const int e = blockIdx.z;
  const float* ip = in + (size_t)e * in_es;
  bf16* op = out + (size_t)e * out_es;
  const int r0 = blockIdx.y * 64, c0 = blockIdx.x * 64;
  const int tc = threadIdx.x & 63, tr = threadIdx.x >> 6;
#pragma unroll
  for (int i = 0; i < 16; ++i) {
    const int r = tr + i * 4;
    tile[r][tc] = ip[(size_t)(r0 + r) * C + c0 + tc];
  }
  __syncthreads();
  const int wr = threadIdx.x & 63, wc0 = threadIdx.x >> 6;
#pragma unroll
  for (int i = 0; i < 16; ++i) {
    const int c = wc0 + i * 4;
    op[(size_t)(c0 + c) * out_rs + r0 + wr] = (bf16)tile[wr][c];
  }
}

// ============ 256x256, BK=32, triple-buffered fine-interleave core ==========
#define PIPE_DECLS                                                   \
  const int t = threadIdx.x;                                         \
  const int lane = t & 63;                                           \
  const int wid = t >> 6;                                            \
  const int wm = wid >> 2, wn = wid & 3;                             \
  const int fr = lane & 15, fg = lane >> 4, fq = lane >> 4;          \
  const int srow = t >> 2;                                           \
  const int sq = (t & 3) ^ ((t >> 3) & 3);                           \
  const int rsl = fg ^ ((fr >> 1) & 3);

#define PHASE0(buf)                                                  \
  bf16x8 bfr[4], af[4];                                              \
  _Pragma("unroll") for (int fj = 0; fj < 4; ++fj) {                 \
    const int row = wn * 64 + fj * 16 + fr;                          \
    bfr[fj] = *(const bf16x8*)((buf) + 16384 + row * 64 + rsl * 16); \
  }                                                                  \
  _Pragma("unroll") for (int fi = 0; fi < 4; ++fi) {                 \
    const int row = wm * 128 + fi * 16 + fr;                         \
    af[fi] = *(const bf16x8*)((buf) + row * 64 + rsl * 16);          \
  }

#define PHASE1_READS(buf)                                            \
  bf16x8 af2[4];                                                     \
  _Pragma("unroll") for (int fi = 0; fi < 4; ++fi) {                 \
    const int row = wm * 128 + (4 + fi) * 16 + fr;                   \
    af2[fi] = *(const bf16x8*)((buf) + row * 64 + rsl * 16);         \
  }

#define MFMA_CLUSTER(A, ACCOFF)                                      \
  __builtin_amdgcn_s_barrier();                                      \
  asm volatile("s_waitcnt lgkmcnt(0)" ::: "memory");                 \
  __builtin_amdgcn_sched_barrier(0);                                 \
  __builtin_amdgcn_s_setprio(1);                                     \
  _Pragma("unroll") for (int fi = 0; fi < 4; ++fi)                   \
  _Pragma("unroll") for (int fj = 0; fj < 4; ++fj)                   \
    acc[(ACCOFF) + fi][fj] = __builtin_amdgcn_mfma_f32_16x16x32_bf16(\
        bfr[fj], (A)[fi], acc[(ACCOFF) + fi][fj], 0, 0, 0);          \
  __builtin_amdgcn_s_setprio(0);

// ---------------- stage 1: persistent over ct, NT burst epilogue ------------
// R13 structure (proven 121us) with __builtin_nontemporal_store on G:
// G is written once and read once by stage2 -- no reuse, so bypass L2
// allocation (avoids RMW allocate fetches + dirty-eviction pressure;
// R13 showed ~24MB excess FETCH, R14's partial-line stores showed +54MB).
__global__ __launch_bounds__(512, 1) void ffn_stage1_f(
    const bf16* __restrict__ xb, const bf16* __restrict__ w1t,
    const float* __restrict__ b1, const float* __restrict__ wts,
    bf16* __restrict__ G) {
  __shared__ __align__(16) char lds[98304];
  __shared__ float b1s[1024];
  __shared__ float wls[256];
  const int mt = blockIdx.x, e = blockIdx.y;
  PIPE_DECLS
  b1s[t] = b1[e * Hh + t];
  b1s[512 + t] = b1[e * Hh + 512 + t];
  if (t < 256) wls[t] = wts[((size_t)mt * 256 + t) * Ee + e];

  const bf16* Ag = xb + (size_t)mt * 256 * Dd;
  const bf16* Bg0 = w1t + (size_t)e * Hh * Dd;

  auto stageA = [&](int it, char* buf) {
    const int k0 = (it & 15) * 32;
    gload_lds16(Ag + (size_t)srow * Dd + k0 + sq * 8, buf + wid * 1024);
    gload_lds16(Ag + (size_t)(128 + srow) * Dd + k0 + sq * 8, buf + 8192 + wid * 1024);
  };
  auto stageB = [&](int it, char* buf) {
    const bf16* Bg = Bg0 + (size_t)(it >> 4) * 256 * Dd;
    const int k0 = (it & 15) * 32;
    gload_lds16(Bg + (size_t)srow * Dd + k0 + sq * 8, buf + 16384 + wid * 1024);
    gload_lds16(Bg + (size_t)(128 + srow) * Dd + k0 + sq * 8, buf + 24576 + wid * 1024);
  };

  f32x4 acc[8][4] = {};
  const int NT = 64;
  stageA(0, lds); stageB(0, lds);
  stageA(1, lds + 32768); stageB(1, lds + 32768);
  for (int it = 0; it < NT; ++it) {
    char* buf = lds + (it % 3) * 32768;
    char* nbuf = lds + ((it + 2) % 3) * 32768;
    if (it + 1 < NT) {
      asm volatile("s_waitcnt vmcnt(4)" ::: "memory");
    } else {
      asm volatile("s_waitcnt vmcnt(0)" ::: "memory");
    }
    __builtin_amdgcn_s_barrier();
    {
      PHASE0(buf)
      if (it + 2 < NT) stageA(it + 2, nbuf);
      MFMA_CLUSTER(af, 0)
      PHASE1_READS(buf)
      if (it + 2 < NT) stageB(it + 2, nbuf);
      MFMA_CLUSTER(af2, 4)
    }
    if ((it & 15) == 15) {
      const int ct = it >> 4;
      bf16* tbase = G + ((((size_t)e * 32 + mt) * 4) + ct) * TSZ;
      float b1v[4][4];
#pragma unroll
      for (int fj = 0; fj < 4; ++fj)
#pragma unroll
        for (int r = 0; r < 4; ++r)
          b1v[fj][r] = b1s[ct * 256 + wn * 64 + fj * 16 + fq * 4 + r];
#pragma unroll
      for (int fi = 0; fi < 8; ++fi) {
        const int mp = wm * 128 + fi * 16 + fr;  // m within tile
        const float wgt = wls[mp];
        bf16* gp = tbase + (size_t)mp * 256 + wn * 64 + fq * 4;
#pragma unroll
        for (int fj = 0; fj < 4; ++fj) {
          bf16x4 o;
#pragma unroll
          for (int r = 0; r < 4; ++r) {
            float v = acc[fi][fj][r] + b1v[fj][r];
            o[r] = (bf16)(gelu_fast(v) * wgt);
          }
          __builtin_nontemporal_store(o, (bf16x4*)(gp + fj * 16));
#pragma unroll
          for (int r = 0; r < 4; ++r) acc[fi][fj][r] = 0.f;
        }
      }
    }
  }
}

// ---------------- stage 2: split-K partial, tiled-G reads, NT P stores ------
__global__ __launch_bounds__(512, 1) void ffn_stage2_f(
    const bf16* __restrict__ G, const bf16* __restrict__ w2t,
    float* __restrict__ P, int eslabs) {
  __shared__ __align__(16) char lds[98304];
  const int mt = blockIdx.x, nt = blockIdx.y, s = blockIdx.z;
  PIPE_DECLS
  const bf16* Bg = w2t + (size_t)nt * 256 * GKS + (size_t)s * eslabs * Hh;

  auto stageA = [&](int it, char* buf) {
    const int eidx = s * eslabs + (it >> 5);
    const int ct = (it >> 3) & 3;
    const int hp = (it & 7) * 32;
    const bf16* tb = G + ((((size_t)eidx * 32 + mt) * 4) + ct) * TSZ;
    gload_lds16(tb + (size_t)srow * 256 + hp + sq * 8, buf + wid * 1024);
    gload_lds16(tb + (size_t)(128 + srow) * 256 + hp + sq * 8, buf + 8192 + wid * 1024);
  };
  auto stageB = [&](int it, char* buf) {
    const int k0 = it * 32;
    gload_lds16(Bg + (size_t)srow * GKS + k0 + sq * 8, buf + 16384 + wid * 1024);
    gload_lds16(Bg + (size_t)(128 + srow) * GKS + k0 + sq * 8, buf + 24576 + wid * 1024);
  };

  f32x4 acc[8][4] = {};
  const int NT = eslabs * 32;
  stageA(0, lds); stageB(0, lds);
  stageA(1, lds + 32768); stageB(1, lds + 32768);
  for (int it = 0; it < NT; ++it) {
    char* buf = lds + (it % 3) * 32768;
    char* nbuf = lds + ((it + 2) % 3) * 32768;
    if (it + 1 < NT) {
      asm volatile("s_waitcnt vmcnt(4)" ::: "memory");
    } else {
      asm volatile("s_waitcnt vmcnt(0)" ::: "memory");
    }
    __builtin_amdgcn_s_barrier();
    {
      PHASE0(buf)
      if (it + 2 < NT) stageA(it + 2, nbuf);
      MFMA_CLUSTER(af, 0)
      PHASE1_READS(buf)
      if (it + 2 < NT) stageB(it + 2, nbuf);
      MFMA_CLUSTER(af2, 4)
    }
  }

  float* Pp = P + (size_t)s * Mm * Dd;
#pragma unroll
  for (int fi = 0; fi < 8; ++fi) {
    const size_t m = (size_t)mt * 256 + wm * 128 + fi * 16 + fr;
    float* pp = Pp + m * Dd + nt * 256 + wn * 64 + fq * 4;
#pragma unroll
    for (int fj = 0; fj < 4; ++fj)
      __builtin_nontemporal_store(acc[fi][fj], (f32x4*)(pp + fj * 16));
  }
}

// ---------------- reduce partials + bias (NT P reads) -----------------------
__global__ __launch_bounds__(256) void reduce_bias(
    const float* __restrict__ P, const float* __restrict__ wts,
    const float* __restrict__ b2, float* __restrict__ out, int S) {
  const int n4 = Mm * Dd / 4;
  int i = blockIdx.x * 256 + threadIdx.x;
  if (i >= n4) return;
  const int m = i / (Dd / 4);
  const int d0 = (i % (Dd / 4)) * 4;
  f32x4 a = __builtin_nontemporal_load((const f32x4*)P + i);
  for (int s = 1; s < S; ++s) {
    f32x4 p = __builtin_nontemporal_load((const f32x4*)P + (size_t)s * n4 + i);
    a += p;
  }
  const float* wr = wts + (size_t)m * Ee;
#pragma unroll
  for (int e = 0; e < Ee; ++e) {
    const float w = wr[e];
    const float* b = b2 + e * Dd + d0;
    a[0] += w * b[0]; a[1] += w * b[1]; a[2] += w * b[2]; a[3] += w * b[3];
  }
  ((f32x4*)out)[i] = a;
}

// ---------------- launch ----------------------------------------------------
extern "C" void kernel_launch(void* const* d_in, const int* in_sizes, int n_in,
                              void* d_out, int out_size, void* d_ws, size_t ws_size,
                              hipStream_t stream) {
  const float* x   = (const float*)d_in[0];
  const float* wts = (const float*)d_in[1];
  const float* w1  = (const float*)d_in[2];
  const float* b1  = (const float*)d_in[3];
  const float* w2  = (const float*)d_in[4];
  const float* b2  = (const float*)d_in[5];
  float* out = (float*)d_out;

  char* ws = (char*)d_ws;
  size_t off = 0;
  bf16* xb  = (bf16*)(ws + off); off += (size_t)Mm * Dd * 2;
  bf16* w1t = (bf16*)(ws + off); off += (size_t)Ee * Hh * Dd * 2;
  bf16* w2t = (bf16*)(ws + off); off += (size_t)Dd * Ee * Hh * 2;

  const size_t gfull = (size_t)Mm * Ee * Hh * 2;  // 134 MB (tiled layout)
  const size_t psz   = (size_t)Mm * Dd * 4;       // 16.8 MB

  cvt_x_kernel<<<(Mm * Dd / 4 + 255) / 256, 256, 0, stream>>>(x, xb, Mm * Dd / 4);
  transpose_cvt<<<dim3(Hh / 64, Dd / 64, Ee), 256, 0, stream>>>(
      w1, w1t, Dd, Hh, (size_t)Dd * Hh, (size_t)Hh * Dd, Dd);
  transpose_cvt<<<dim3(Dd / 64, Hh / 64, Ee), 256, 0, stream>>>(
      w2, w2t, Hh, Dd, (size_t)Hh * Dd, (size_t)Hh, Ee * Hh);

  int S = 0;
  if (ws_size >= off + gfull + 4 * psz) S = 4;
  else if (ws_size >= off + gfull + 2 * psz) S = 2;

  if (S >= 2) {
    bf16* G = (bf16*)(ws + off);
    float* P = (float*)(ws + off + gfull);
    ffn_stage1_f<<<dim3(Mm / 256, Ee), 512, 0, stream>>>(
        xb, w1t, b1, wts, G);
    ffn_stage2_f<<<dim3(Mm / 256, Dd / 256, S), 512, 0, stream>>>(
        G, w2t, P, Ee / S);
    reduce_bias<<<(Mm * Dd / 4 + 255) / 256, 256, 0, stream>>>(P, wts, b2, out, S);
  }
}

// Round 16
// 215.325 us; speedup vs baseline: 1.2468x; 1.1755x over previous
//
#include <hip/hip_runtime.h>
#include <hip/hip_bf16.h>

#define DEV __device__ __forceinline__

typedef __bf16 bf16;
typedef __bf16 bf16x4 __attribute__((ext_vector_type(4)));
typedef __bf16 bf16x8 __attribute__((ext_vector_type(8)));
typedef float f32x4 __attribute__((ext_vector_type(4)));

static constexpr int Bb = 4, Ll = 2048, Dd = 512, Ee = 8, Hh = 1024;
static constexpr int Mm = Bb * Ll;  // 8192 tokens
static constexpr int GKS = Ee * Hh; // 8192 (w2t row stride)
// G stored BLOCK-TILED: tile (e, mt, ct) = [256 m'][256 h'] contiguous 128KB.
static constexpr int TSZ = 65536;   // elements per tile

// ---------------- async global->LDS (16B per lane, wave-uniform LDS base) ---
DEV void gload_lds16(const void* g, void* l) {
  __builtin_amdgcn_global_load_lds(
      (const __attribute__((address_space(1))) unsigned int*)g,
      (__attribute__((address_space(3))) unsigned int*)l, 16, 0, 0);
}

// fast exact-enough gelu: tanh form, g = h - h/(exp(2y)+1)
DEV float gelu_fast(float h) {
  const float k = 0.7978845608028654f * 2.0f * 1.4426950408889634f;
  float h2 = h * h;
  float y = h * (k + (0.044715f * k) * h2);
  float t = exp2f(y);
  return h - h * __frcp_rn(t + 1.0f);
}

// ---------------- elementwise f32 -> bf16 -----------------------------------
__global__ void cvt_x_kernel(const float* __restrict__ in, bf16* __restrict__ out, int n4) {
  int i = blockIdx.x * blockDim.x + threadIdx.x;
  if (i < n4) {
    float4 v = ((const float4*)in)[i];
    bf16x4 o = {(bf16)v.x, (bf16)v.y, (bf16)v.z, (bf16)v.w};
    ((bf16x4*)out)[i] = o;
  }
}

// ---------------- tiled transpose + convert (float4 reads, G13) -------------
__global__ void transpose_cvt(const float* __restrict__ in, bf16* __restrict__ out,
                              int R, int C, size_t in_es, size_t out_es, int out_rs) {
  __shared__ float tile[64][65];
  const int e = blockIdx.z;
  const float* ip = in + (size_t)e * in_es;
  bf16* op = out + (size_t)e * out_es;
  const int r0 = blockIdx.y * 64, c0 = blockIdx.x * 64;
  const int rr = threadIdx.x >> 4, c4 = (threadIdx.x & 15) * 4;
#pragma unroll
  for (int i = 0; i < 4; ++i) {
    const int r = rr + i * 16;
    float4 v = *(const float4*)(ip + (size_t)(r0 + r) * C + c0 + c4);
    tile[r][c4] = v.x; tile[r][c4 + 1] = v.y;
    tile[r][c4 + 2] = v.z; tile[r][c4 + 3] = v.w;
  }
  __syncthreads();
  const int wr = threadIdx.x & 63, wc0 = threadIdx.x >> 6;
#pragma unroll
  for (int i = 0; i < 16; ++i) {
    const int c = wc0 + i * 4;
    op[(size_t)(c0 + c) * out_rs + r0 + wr] = (bf16)tile[wr][c];
  }
}

// ============ 256x256, BK=32, triple-buffered fine-interleave core ==========
#define PIPE_DECLS                                                   \
  const int t = threadIdx.x;                                         \
  const int lane = t & 63;                                           \
  const int wid = t >> 6;                                            \
  const int wm = wid >> 2, wn = wid & 3;                             \
  const int fr = lane & 15, fg = lane >> 4, fq = lane >> 4;          \
  const int srow = t >> 2;                                           \
  const int sq = (t & 3) ^ ((t >> 3) & 3);                           \
  const int rsl = fg ^ ((fr >> 1) & 3);

#define PHASE0(buf)                                                  \
  bf16x8 bfr[4], af[4];                                              \
  _Pragma("unroll") for (int fj = 0; fj < 4; ++fj) {                 \
    const int row = wn * 64 + fj * 16 + fr;                          \
    bfr[fj] = *(const bf16x8*)((buf) + 16384 + row * 64 + rsl * 16); \
  }                                                                  \
  _Pragma("unroll") for (int fi = 0; fi < 4; ++fi) {                 \
    const int row = wm * 128 + fi * 16 + fr;                         \
    af[fi] = *(const bf16x8*)((buf) + row * 64 + rsl * 16);          \
  }

#define PHASE1_READS(buf)                                            \
  bf16x8 af2[4];                                                     \
  _Pragma("unroll") for (int fi = 0; fi < 4; ++fi) {                 \
    const int row = wm * 128 + (4 + fi) * 16 + fr;                   \
    af2[fi] = *(const bf16x8*)((buf) + row * 64 + rsl * 16);         \
  }

#define MFMA_CLUSTER(A, ACCOFF)                                      \
  __builtin_amdgcn_s_barrier();                                      \
  asm volatile("s_waitcnt lgkmcnt(0)" ::: "memory");                 \
  __builtin_amdgcn_sched_barrier(0);                                 \
  __builtin_amdgcn_s_setprio(1);                                     \
  _Pragma("unroll") for (int fi = 0; fi < 4; ++fi)                   \
  _Pragma("unroll") for (int fj = 0; fj < 4; ++fj)                   \
    acc[(ACCOFF) + fi][fj] = __builtin_amdgcn_mfma_f32_16x16x32_bf16(\
        bfr[fj], (A)[fi], acc[(ACCOFF) + fi][fj], 0, 0, 0);          \
  __builtin_amdgcn_s_setprio(0);

// ---------------- stage 1: persistent over ct, cached burst epilogue --------
// (R13 proven: plain full-line stores; NT 8B stores amplify writes 2.3x --R15)
__global__ __launch_bounds__(512, 1) void ffn_stage1_f(
    const bf16* __restrict__ xb, const bf16* __restrict__ w1t,
    const float* __restrict__ b1, const float* __restrict__ wts,
    bf16* __restrict__ G) {
  __shared__ __align__(16) char lds[98304];
  __shared__ float b1s[1024];
  __shared__ float wls[256];
  const int mt = blockIdx.x, e = blockIdx.y;
  PIPE_DECLS
  b1s[t] = b1[e * Hh + t];
  b1s[512 + t] = b1[e * Hh + 512 + t];
  if (t < 256) wls[t] = wts[((size_t)mt * 256 + t) * Ee + e];

  const bf16* Ag = xb + (size_t)mt * 256 * Dd;
  const bf16* Bg0 = w1t + (size_t)e * Hh * Dd;

  auto stageA = [&](int it, char* buf) {
    const int k0 = (it & 15) * 32;
    gload_lds16(Ag + (size_t)srow * Dd + k0 + sq * 8, buf + wid * 1024);
    gload_lds16(Ag + (size_t)(128 + srow) * Dd + k0 + sq * 8, buf + 8192 + wid * 1024);
  };
  auto stageB = [&](int it, char* buf) {
    const bf16* Bg = Bg0 + (size_t)(it >> 4) * 256 * Dd;
    const int k0 = (it & 15) * 32;
    gload_lds16(Bg + (size_t)srow * Dd + k0 + sq * 8, buf + 16384 + wid * 1024);
    gload_lds16(Bg + (size_t)(128 + srow) * Dd + k0 + sq * 8, buf + 24576 + wid * 1024);
  };

  f32x4 acc[8][4] = {};
  const int NT = 64;
  stageA(0, lds); stageB(0, lds);
  stageA(1, lds + 32768); stageB(1, lds + 32768);
  for (int it = 0; it < NT; ++it) {
    char* buf = lds + (it % 3) * 32768;
    char* nbuf = lds + ((it + 2) % 3) * 32768;
    if (it + 1 < NT) {
      asm volatile("s_waitcnt vmcnt(4)" ::: "memory");
    } else {
      asm volatile("s_waitcnt vmcnt(0)" ::: "memory");
    }
    __builtin_amdgcn_s_barrier();
    {
      PHASE0(buf)
      if (it + 2 < NT) stageA(it + 2, nbuf);
      MFMA_CLUSTER(af, 0)
      PHASE1_READS(buf)
      if (it + 2 < NT) stageB(it + 2, nbuf);
      MFMA_CLUSTER(af2, 4)
    }
    if ((it & 15) == 15) {
      const int ct = it >> 4;
      bf16* tbase = G + ((((size_t)e * 32 + mt) * 4) + ct) * TSZ;
      float b1v[4][4];
#pragma unroll
      for (int fj = 0; fj < 4; ++fj)
#pragma unroll
        for (int r = 0; r < 4; ++r)
          b1v[fj][r] = b1s[ct * 256 + wn * 64 + fj * 16 + fq * 4 + r];
#pragma unroll
      for (int fi = 0; fi < 8; ++fi) {
        const int mp = wm * 128 + fi * 16 + fr;  // m within tile
        const float wgt = wls[mp];
        bf16* gp = tbase + (size_t)mp * 256 + wn * 64 + fq * 4;
#pragma unroll
        for (int fj = 0; fj < 4; ++fj) {
          bf16x4 o;
#pragma unroll
          for (int r = 0; r < 4; ++r) {
            float v = acc[fi][fj][r] + b1v[fj][r];
            o[r] = (bf16)(gelu_fast(v) * wgt);
          }
          *(bf16x4*)(gp + fj * 16) = o;
#pragma unroll
          for (int r = 0; r < 4; ++r) acc[fi][fj][r] = 0.f;
        }
      }
    }
  }
}

// ---------------- stage 2: split-K partial -> BF16 P ------------------------
__global__ __launch_bounds__(512, 1) void ffn_stage2_f(
    const bf16* __restrict__ G, const bf16* __restrict__ w2t,
    bf16* __restrict__ P, int eslabs) {
  __shared__ __align__(16) char lds[98304];
  const int mt = blockIdx.x, nt = blockIdx.y, s = blockIdx.z;
  PIPE_DECLS
  const bf16* Bg = w2t + (size_t)nt * 256 * GKS + (size_t)s * eslabs * Hh;

  auto stageA = [&](int it, char* buf) {
    const int eidx = s * eslabs + (it >> 5);
    const int ct = (it >> 3) & 3;
    const int hp = (it & 7) * 32;
    const bf16* tb = G + ((((size_t)eidx * 32 + mt) * 4) + ct) * TSZ;
    gload_lds16(tb + (size_t)srow * 256 + hp + sq * 8, buf + wid * 1024);
    gload_lds16(tb + (size_t)(128 + srow) * 256 + hp + sq * 8, buf + 8192 + wid * 1024);
  };
  auto stageB = [&](int it, char* buf) {
    const int k0 = it * 32;
    gload_lds16(Bg + (size_t)srow * GKS + k0 + sq * 8, buf + 16384 + wid * 1024);
    gload_lds16(Bg + (size_t)(128 + srow) * GKS + k0 + sq * 8, buf + 24576 + wid * 1024);
  };

  f32x4 acc[8][4] = {};
  const int NT = eslabs * 32;
  stageA(0, lds); stageB(0, lds);
  stageA(1, lds + 32768); stageB(1, lds + 32768);
  for (int it = 0; it < NT; ++it) {
    char* buf = lds + (it % 3) * 32768;
    char* nbuf = lds + ((it + 2) % 3) * 32768;
    if (it + 1 < NT) {
      asm volatile("s_waitcnt vmcnt(4)" ::: "memory");
    } else {
      asm volatile("s_waitcnt vmcnt(0)" ::: "memory");
    }
    __builtin_amdgcn_s_barrier();
    {
      PHASE0(buf)
      if (it + 2 < NT) stageA(it + 2, nbuf);
      MFMA_CLUSTER(af, 0)
      PHASE1_READS(buf)
      if (it + 2 < NT) stageB(it + 2, nbuf);
      MFMA_CLUSTER(af2, 4)
    }
  }

  bf16* Pp = P + (size_t)s * Mm * Dd;
#pragma unroll
  for (int fi = 0; fi < 8; ++fi) {
    const size_t m = (size_t)mt * 256 + wm * 128 + fi * 16 + fr;
    bf16* pp = Pp + m * Dd + nt * 256 + wn * 64 + fq * 4;
#pragma unroll
    for (int fj = 0; fj < 4; ++fj) {
      bf16x4 o = {(bf16)acc[fi][fj][0], (bf16)acc[fi][fj][1],
                  (bf16)acc[fi][fj][2], (bf16)acc[fi][fj][3]};
      *(bf16x4*)(pp + fj * 16) = o;
    }
  }
}

// ---------------- reduce bf16 partials + bias --------------------------------
typedef short short4v __attribute__((ext_vector_type(4)));
__global__ __launch_bounds__(256) void reduce_bias(
    const bf16* __restrict__ P, const float* __restrict__ wts,
    const float* __restrict__ b2, float* __restrict__ out, int S) {
  const int n4 = Mm * Dd / 4;
  int i = blockIdx.x * 256 + threadIdx.x;
  if (i >= n4) return;
  const int m = i / (Dd / 4);
  const int d0 = (i % (Dd / 4)) * 4;
  f32x4 a = {0.f, 0.f, 0.f, 0.f};
  for (int s = 0; s < S; ++s) {
    bf16x4 p = ((const bf16x4*)P)[(size_t)s * n4 + i];
#pragma unroll
    for (int r = 0; r < 4; ++r) a[r] += (float)p[r];
  }
  const float* wr = wts + (size_t)m * Ee;
#pragma unroll
  for (int e = 0; e < Ee; ++e) {
    const float w = wr[e];
    const float* b = b2 + e * Dd + d0;
    a[0] += w * b[0]; a[1] += w * b[1]; a[2] += w * b[2]; a[3] += w * b[3];
  }
  ((f32x4*)out)[i] = a;
}

// ---------------- launch ----------------------------------------------------
extern "C" void kernel_launch(void* const* d_in, const int* in_sizes, int n_in,
                              void* d_out, int out_size, void* d_ws, size_t ws_size,
                              hipStream_t stream) {
  const float* x   = (const float*)d_in[0];
  const float* wts = (const float*)d_in[1];
  const float* w1  = (const float*)d_in[2];
  const float* b1  = (const float*)d_in[3];
  const float* w2  = (const float*)d_in[4];
  const float* b2  = (const float*)d_in[5];
  float* out = (float*)d_out;

  char* ws = (char*)d_ws;
  size_t off = 0;
  bf16* xb  = (bf16*)(ws + off); off += (size_t)Mm * Dd * 2;
  bf16* w1t = (bf16*)(ws + off); off += (size_t)Ee * Hh * Dd * 2;
  bf16* w2t = (bf16*)(ws + off); off += (size_t)Dd * Ee * Hh * 2;

  const size_t gfull = (size_t)Mm * Ee * Hh * 2;  // 134 MB (tiled layout)
  const size_t psz   = (size_t)Mm * Dd * 2;       // 8.4 MB per bf16 partial

  cvt_x_kernel<<<(Mm * Dd / 4 + 255) / 256, 256, 0, stream>>>(x, xb, Mm * Dd / 4);
  transpose_cvt<<<dim3(Hh / 64, Dd / 64, Ee), 256, 0, stream>>>(
      w1, w1t, Dd, Hh, (size_t)Dd * Hh, (size_t)Hh * Dd, Dd);
  transpose_cvt<<<dim3(Dd / 64, Hh / 64, Ee), 256, 0, stream>>>(
      w2, w2t, Hh, Dd, (size_t)Hh * Dd, (size_t)Hh, Ee * Hh);

  int S = 0;
  if (ws_size >= off + gfull + 4 * psz) S = 4;
  else if (ws_size >= off + gfull + 2 * psz) S = 2;

  if (S >= 2) {
    bf16* G = (bf16*)(ws + off);
    bf16* P = (bf16*)(ws + off + gfull);
    ffn_stage1_f<<<dim3(Mm / 256, Ee), 512, 0, stream>>>(
        xb, w1t, b1, wts, G);
    ffn_stage2_f<<<dim3(Mm / 256, Dd / 256, S), 512, 0, stream>>>(
        G, w2t, P, Ee / S);
    reduce_bias<<<(Mm * Dd / 4 + 255) / 256, 256, 0, stream>>>(P, wts, b2, out, S);
  }
}